// Round 7
// baseline (387.389 us; speedup 1.0000x reference)
//
#include <hip/hip_runtime.h>

// Problem constants
#define RR_ 16      // num_rels
#define N2_ 8192
#define N1_ 1024
#define NOUT_ 256
#define F_ 128
#define E_ 64
#define C_ 32
#define KBIG_ 131072   // R*N2

typedef __attribute__((ext_vector_type(4))) float f32x4;
typedef __attribute__((ext_vector_type(8))) short short8;
typedef __attribute__((ext_vector_type(4))) short s16x4;

#define MFMA(a,b,c) __builtin_amdgcn_mfma_f32_16x16x32_bf16((a),(b),(c),0,0,0)

__device__ __forceinline__ unsigned short f2bf(float f) {
  unsigned int u = __builtin_bit_cast(unsigned int, f);
  u += 0x7fffu + ((u >> 16) & 1u);              // RNE
  return (unsigned short)(u >> 16);
}

__device__ __forceinline__ short8 cvt8(f32x4 v0, f32x4 v1) {
  short8 r;
  r[0] = (short)f2bf(v0[0]); r[1] = (short)f2bf(v0[1]);
  r[2] = (short)f2bf(v0[2]); r[3] = (short)f2bf(v0[3]);
  r[4] = (short)f2bf(v1[0]); r[5] = (short)f2bf(v1[1]);
  r[6] = (short)f2bf(v1[2]); r[7] = (short)f2bf(v1[3]);
  return r;
}

// ---------------------------------------------------------------------------
// K1: prep — w1T[r][h][f], w2T[r][c][h] (bf16). grid: 40 blocks x 256
// ---------------------------------------------------------------------------
__global__ __launch_bounds__(256) void k_prep(
    const float* __restrict__ comp1, const float* __restrict__ bases1,
    const float* __restrict__ comp2, const float* __restrict__ bases2,
    short* __restrict__ w1T, short* __restrict__ w2T)
{
  int bid = blockIdx.x, t = threadIdx.x;
  if (bid < 32) {                       // w1T[r][h][f] = sum_b comp1[r][b]*bases1[b][f][h]
    int base = bid * 4096;
    for (int i = 0; i < 16; ++i) {
      int e = base + i * 256 + t;
      int r = e >> 13, rem = e & 8191;
      int h = rem >> 7, f = rem & 127;
      float s = 0.f;
      #pragma unroll
      for (int b = 0; b < 16; ++b) s += comp1[r * 16 + b] * bases1[b * 8192 + f * 64 + h];
      w1T[e] = (short)f2bf(s);
    }
  } else {                              // w2T[r][c][h] = sum_b comp2[r][b]*bases2[b][h][c]
    int base = (bid - 32) * 4096;
    for (int i = 0; i < 16; ++i) {
      int e = base + i * 256 + t;
      int r = e >> 11, rem = e & 2047;
      int c = rem >> 6, h = rem & 63;
      float s = 0.f;
      #pragma unroll
      for (int b = 0; b < 16; ++b) s += comp2[r * 16 + b] * bases2[b * 2048 + h * 32 + c];
      w2T[e] = (short)f2bf(s);
    }
  }
}

// ---------------------------------------------------------------------------
// K2: xwT[h][r*8192+n2] = sum_f w1T[r][h][f] * X[sel[n2]][f]
// per r: GEMM M=64(h) x N=8192(n2) x K=128(f). 4096 waves, grid 1024x256.
// ---------------------------------------------------------------------------
__global__ __launch_bounds__(256) void k_xw(
    const float* __restrict__ X, const int* __restrict__ sel,
    const short* __restrict__ w1T, short* __restrict__ xwT)
{
  int w = blockIdx.x * 4 + (threadIdx.x >> 6);
  int lane = threadIdx.x & 63, lr = lane & 15, lg = lane >> 4;
  int r = w >> 8;
  int n0 = (w & 255) * 32;

  // sel may be int64 (jax x64) — detect via arange pattern, values fit int32.
  bool is64 = (sel[1] == 0 && sel[2] == 1);
  int i0 = is64 ? sel[2 * (n0 + lr)] : sel[n0 + lr];
  int i1 = is64 ? sel[2 * (n0 + 16 + lr)] : sel[n0 + 16 + lr];

  const short* aBase = w1T + r * 8192 + lr * 128 + 8 * lg;
  const float* b0p = X + (size_t)i0 * 128 + 8 * lg;
  const float* b1p = X + (size_t)i1 * 128 + 8 * lg;

  f32x4 acc[4][2] = {};
  #pragma unroll
  for (int ks = 0; ks < 4; ++ks) {
    short8 a[4];
    #pragma unroll
    for (int mf = 0; mf < 4; ++mf)
      a[mf] = *(const short8*)(aBase + mf * 2048 + ks * 32);
    short8 b[2];
    b[0] = cvt8(*(const f32x4*)(b0p + ks * 32), *(const f32x4*)(b0p + ks * 32 + 4));
    b[1] = cvt8(*(const f32x4*)(b1p + ks * 32), *(const f32x4*)(b1p + ks * 32 + 4));
    #pragma unroll
    for (int mf = 0; mf < 4; ++mf)
      #pragma unroll
      for (int nf = 0; nf < 2; ++nf)
        acc[mf][nf] = MFMA(a[mf], b[nf], acc[mf][nf]);
  }
  #pragma unroll
  for (int mf = 0; mf < 4; ++mf)
    #pragma unroll
    for (int nf = 0; nf < 2; ++nf)
      #pragma unroll
      for (int rr = 0; rr < 4; ++rr) {
        int h = mf * 16 + 4 * lg + rr;
        int col = r * 8192 + n0 + nf * 16 + lr;
        xwT[(size_t)h * KBIG_ + col] = (short)f2bf(acc[mf][nf][rr]);
      }
}

// ---------------------------------------------------------------------------
// K_conv: A0 (fp32, row-major, 537MB) -> A0bf (bf16, GEMM-TILED, 268MB).
// Piece p (m = p>>6, ch = p&63) = 2048 floats, read PERFECTLY SEQUENTIALLY
// across the machine (piece = i*8192 + gwid: 64MB sliding window, copy-like).
// Reads are NONTEMPORAL (dead fp32 must not evict A0bf from L3).
// Out layout: [mt 0..63][ch 0..63][r 0..15][2048 k] bf16 — each (mt,ch)
// wave-tile of k_h1_tiled is one contiguous 64KB region.
// 2048 blocks x 256 thr = 8192 waves x 8 pieces.
// ---------------------------------------------------------------------------
__global__ __launch_bounds__(256) void k_conv(
    const float* __restrict__ A0, short* __restrict__ A0bf)
{
  int gw = (blockIdx.x * 256 + threadIdx.x) >> 6;   // 0..8191
  int lane = threadIdx.x & 63;
  for (int i = 0; i < 8; ++i) {
    int p = i * 8192 + gw;
    int m = p >> 6, ch = p & 63;
    int mt = m >> 4, r = m & 15;
    const float* inb = A0 + (size_t)p * 2048;
    short* outb = A0bf + ((size_t)(mt * 64 + ch) * 16 + r) * 2048;
    #pragma unroll
    for (int j = 0; j < 8; ++j) {
      f32x4 v = __builtin_nontemporal_load((const f32x4*)(inb + j * 256 + lane * 4));
      s16x4 o;
      o[0] = (short)f2bf(v[0]); o[1] = (short)f2bf(v[1]);
      o[2] = (short)f2bf(v[2]); o[3] = (short)f2bf(v[3]);
      *(s16x4*)(outb + j * 256 + lane * 4) = o;
    }
  }
}

// ---------------------------------------------------------------------------
// K3 (v5): h1p[ch][m][h] partials from TILED bf16 A.  LDS-free MFMA GEMM.
// 4096 waves (mt 0..63 x ch 0..63) = 1024 blocks x 256 thr, 4 blocks/CU.
// Each wave: 16 rows x 2048 k from ONE contiguous 64KB A-region (L3-hot),
// B (xwT chunk, L2/L3-hot) direct. No barriers, no waitcnt games — TLP
// (16 waves/CU) hides latency.
// ---------------------------------------------------------------------------
__global__ __launch_bounds__(256, 4) void k_h1_tiled(
    const short* __restrict__ A0bf, const short* __restrict__ xwT,
    float* __restrict__ h1p)
{
  int wave = blockIdx.x * 4 + (threadIdx.x >> 6);
  int lane = threadIdx.x & 63, lr = lane & 15, lg = lane >> 4;
  int mt = wave >> 6;          // 0..63
  int ch = wave & 63;          // 0..63

  const short* ab = A0bf + (size_t)(mt * 64 + ch) * 32768 + lr * 2048 + 8 * lg;
  const short* bb = xwT + (size_t)lr * KBIG_ + ch * 2048 + 8 * lg;

  f32x4 acc[4] = {};
  #pragma unroll 4
  for (int kk = 0; kk < 64; ++kk) {
    short8 a = *(const short8*)(ab + kk * 32);
    #pragma unroll
    for (int nf = 0; nf < 4; ++nf) {
      short8 b = *(const short8*)(bb + (size_t)nf * 16 * KBIG_ + kk * 32);
      acc[nf] = MFMA(a, b, acc[nf]);
    }
  }

  float* basep = h1p + (size_t)ch * 65536;
  #pragma unroll
  for (int nf = 0; nf < 4; ++nf)
    #pragma unroll
    for (int rr = 0; rr < 4; ++rr)
      basep[(mt * 16 + 4 * lg + rr) * 64 + nf * 16 + lr] = acc[nf][rr];
}

// ---------------------------------------------------------------------------
// Fallback K3 (v4): wave-private LDS pipeline reading A0 fp32 directly.
// Used only when ws_size can't hold A0bf.
// ---------------------------------------------------------------------------
__device__ __forceinline__ void stageA(const float* aRow0, int s, int lane,
                                       float* ldsBase) {
  const float* rbase = aRow0 + (size_t)s * 256;
  #pragma unroll
  for (int j = 0; j < 16; ++j) {
    const float* gp = rbase + (size_t)j * KBIG_ +
        ((((unsigned)lane * 16u) ^ (((unsigned)j & 7u) << 4)) >> 2);
    __builtin_amdgcn_global_load_lds(
        (const __attribute__((address_space(1))) void*)gp,
        (__attribute__((address_space(3))) void*)(ldsBase + j * 256), 16, 0, 0);
  }
}

__global__ __launch_bounds__(256) void k_h1_direct(
    const float* __restrict__ A0, const short* __restrict__ xwT,
    float* __restrict__ h1p)
{
  __shared__ float As[4][2][16][256];
  const int tid  = threadIdx.x;
  const int w    = tid >> 6;
  const int lane = tid & 63, lr = lane & 15, lg = lane >> 4;
  const int mt = blockIdx.x >> 4;
  const int ch = blockIdx.x & 15;
  const int m0 = mt * 64 + w * 16;
  const size_t kc = (size_t)ch * 8192;

  const float* aRow0 = A0 + (size_t)m0 * KBIG_ + kc;
  const short* bb    = xwT + (size_t)lr * KBIG_ + kc + 8 * lg;
  float* myLds0 = &As[w][0][0][0];
  float* myLds1 = &As[w][1][0][0];

  f32x4 acc[4] = {};
  const unsigned swz = (unsigned)(lr & 7) * 4;

  stageA(aRow0, 0, lane, myLds0);

  for (int s = 0; s < 32; ++s) {
    float* cur = (s & 1) ? myLds1 : myLds0;
    float* nxt = (s & 1) ? myLds0 : myLds1;

    short8 b[8][4];
    #pragma unroll
    for (int ks = 0; ks < 8; ++ks)
      #pragma unroll
      for (int nf = 0; nf < 4; ++nf)
        b[ks][nf] = *(const short8*)(bb + (size_t)nf * 16 * KBIG_ + s * 256 + ks * 32);
    __builtin_amdgcn_sched_barrier(0);

    if (s + 1 < 32) {
      stageA(aRow0, s + 1, lane, nxt);
      asm volatile("s_waitcnt vmcnt(16)" ::: "memory");
    } else {
      asm volatile("s_waitcnt vmcnt(0)" ::: "memory");
    }
    __builtin_amdgcn_sched_barrier(0);

    const float* lrow = cur + lr * 256;
    #pragma unroll
    for (int ks = 0; ks < 8; ++ks) {
      unsigned c0 = ((unsigned)(ks * 32 + 8 * lg)) ^ swz;
      unsigned c1 = ((unsigned)(ks * 32 + 8 * lg + 4)) ^ swz;
      f32x4 v0 = *(const f32x4*)(lrow + c0);
      f32x4 v1 = *(const f32x4*)(lrow + c1);
      short8 a = cvt8(v0, v1);
      #pragma unroll
      for (int nf = 0; nf < 4; ++nf)
        acc[nf] = MFMA(a, b[ks][nf], acc[nf]);
    }
  }

  float* basep = h1p + (size_t)ch * 65536 + (size_t)m0 * 64;
  #pragma unroll
  for (int nf = 0; nf < 4; ++nf)
    #pragma unroll
    for (int rr = 0; rr < 4; ++rr)
      basep[(4 * lg + rr) * 64 + nf * 16 + lr] = acc[nf][rr];
}

// ---------------------------------------------------------------------------
// K3b: h1b[m][h] = bf16(relu(sum_{c<nch} h1p[c][m][h] + bias1[h]))
// ---------------------------------------------------------------------------
__global__ __launch_bounds__(256) void k_red(
    const float* __restrict__ h1p, const float* __restrict__ bias1,
    short* __restrict__ h1b, int nch)
{
  int e = (blockIdx.x * 256 + threadIdx.x) * 4;
  f32x4 s = {0.f, 0.f, 0.f, 0.f};
  #pragma unroll 8
  for (int c = 0; c < nch; ++c) {
    f32x4 v = *(const f32x4*)(h1p + (size_t)c * 65536 + e);
    s += v;
  }
  int h = e & 63;
  s16x4 o;
  #pragma unroll
  for (int j = 0; j < 4; ++j) {
    float x = s[j] + bias1[h + j];
    x = x > 0.f ? x : 0.f;
    o[j] = (short)f2bf(x);
  }
  *(s16x4*)(h1b + e) = o;
}

// ---------------------------------------------------------------------------
// K4a: H2T[c][r*1024+m] = sum_h w2T[r][c][h] * h1b[m][h]
// ---------------------------------------------------------------------------
__global__ __launch_bounds__(256) void k_h2(
    const short* __restrict__ w2T, const short* __restrict__ h1b,
    short* __restrict__ H2T)
{
  int w = blockIdx.x * 4 + (threadIdx.x >> 6);
  int lane = threadIdx.x & 63, lr = lane & 15, lg = lane >> 4;
  int r = w >> 4;
  int n0 = (w & 15) * 64;

  f32x4 acc[2][4] = {};
  #pragma unroll
  for (int ks = 0; ks < 2; ++ks) {
    short8 a[2];
    #pragma unroll
    for (int mf = 0; mf < 2; ++mf)
      a[mf] = *(const short8*)(w2T + r * 2048 + (mf * 16 + lr) * 64 + ks * 32 + 8 * lg);
    short8 b[4];
    #pragma unroll
    for (int nf = 0; nf < 4; ++nf)
      b[nf] = *(const short8*)(h1b + (size_t)(n0 + nf * 16 + lr) * 64 + ks * 32 + 8 * lg);
    #pragma unroll
    for (int mf = 0; mf < 2; ++mf)
      #pragma unroll
      for (int nf = 0; nf < 4; ++nf)
        acc[mf][nf] = MFMA(a[mf], b[nf], acc[mf][nf]);
  }
  #pragma unroll
  for (int mf = 0; mf < 2; ++mf)
    #pragma unroll
    for (int nf = 0; nf < 4; ++nf)
      #pragma unroll
      for (int rr = 0; rr < 4; ++rr) {
        int c = mf * 16 + 4 * lg + rr;
        int col = r * 1024 + n0 + nf * 16 + lr;
        H2T[(size_t)c * 16384 + col] = (short)f2bf(acc[mf][nf][rr]);
      }
}

// ---------------------------------------------------------------------------
// K4b: outp[ch][m][c] partials of A1[256 x 16384] @ H2 (B^T = H2T). Split-K.
// ---------------------------------------------------------------------------
__global__ __launch_bounds__(256) void k_out(
    const float* __restrict__ A1, const short* __restrict__ H2T,
    float* __restrict__ outp)
{
  int w = blockIdx.x * 4 + (threadIdx.x >> 6);
  int lane = threadIdx.x & 63, lr = lane & 15, lg = lane >> 4;
  int mt = w >> 7;
  int ch = w & 127;
  int m0 = mt * 64;
  size_t kc = (size_t)ch * 128;

  const float* aBase = A1 + (size_t)(m0 + lr) * 16384 + kc + 8 * lg;
  const short* bBase = H2T + (size_t)lr * 16384 + kc + 8 * lg;

  f32x4 acc[4][2] = {};
  #pragma unroll
  for (int ks = 0; ks < 4; ++ks) {
    short8 a[4];
    #pragma unroll
    for (int mf = 0; mf < 4; ++mf) {
      const float* p = aBase + (size_t)mf * 16 * 16384 + ks * 32;
      f32x4 v0 = *(const f32x4*)p;
      f32x4 v1 = *((const f32x4*)p + 1);
      a[mf] = cvt8(v0, v1);
    }
    short8 b[2];
    #pragma unroll
    for (int nf = 0; nf < 2; ++nf)
      b[nf] = *(const short8*)(bBase + (size_t)nf * 16 * 16384 + ks * 32);
    #pragma unroll
    for (int mf = 0; mf < 4; ++mf)
      #pragma unroll
      for (int nf = 0; nf < 2; ++nf)
        acc[mf][nf] = MFMA(a[mf], b[nf], acc[mf][nf]);
  }
  float* base = outp + (size_t)ch * 8192;
  #pragma unroll
  for (int mf = 0; mf < 4; ++mf)
    #pragma unroll
    for (int nf = 0; nf < 2; ++nf)
      #pragma unroll
      for (int rr = 0; rr < 4; ++rr)
        base[(m0 + mf * 16 + 4 * lg + rr) * 32 + nf * 16 + lr] = acc[mf][nf][rr];
}

// ---------------------------------------------------------------------------
// K5: out[m][c] = sum_ch outp[ch][m][c] + bias2[c]
// ---------------------------------------------------------------------------
__global__ __launch_bounds__(256) void k_outred(
    const float* __restrict__ outp, const float* __restrict__ bias2,
    float* __restrict__ out)
{
  int e = (blockIdx.x * 256 + threadIdx.x) * 4;
  f32x4 s = {0.f, 0.f, 0.f, 0.f};
  #pragma unroll 8
  for (int c = 0; c < 128; ++c) {
    f32x4 v = *(const f32x4*)(outp + (size_t)c * 8192 + e);
    s += v;
  }
  int cc = e & 31;
  f32x4 o;
  #pragma unroll
  for (int j = 0; j < 4; ++j)
    o[j] = s[j] + bias2[cc + j];
  *(f32x4*)(out + e) = o;
}

// ---------------------------------------------------------------------------
extern "C" void kernel_launch(void* const* d_in, const int* in_sizes, int n_in,
                              void* d_out, int out_size, void* d_ws, size_t ws_size,
                              hipStream_t stream) {
  (void)in_sizes; (void)n_in; (void)out_size;
  const float* X      = (const float*)d_in[0];
  const int*   sel    = (const int*)  d_in[1];
  const float* A0     = (const float*)d_in[2];
  const float* A1     = (const float*)d_in[3];
  const float* comp1  = (const float*)d_in[4];
  const float* bases1 = (const float*)d_in[5];
  const float* comp2  = (const float*)d_in[6];
  const float* bases2 = (const float*)d_in[7];
  const float* bias1  = (const float*)d_in[8];
  const float* bias2  = (const float*)d_in[9];
  float* out = (float*)d_out;

  char* ws = (char*)d_ws;
  short* w1T = (short*)(ws);                 //    262144 B  [16][64][128]   bf16
  short* w2T = (short*)(ws + 262144);        //     65536 B  [16][32][64]    bf16
  short* xwT = (short*)(ws + 327680);        //  16777216 B  [64][131072]    bf16
  float* h1p = (float*)(ws + 17104896);      //  16777216 B  [<=64][1024][64] f32
  short* h1b = (short*)(ws + 33882112);      //    131072 B  [1024][64]      bf16
  short* H2T = (short*)(ws + 34013184);      //   1048576 B  [32][16384]     bf16
  float* outp= (float*)(ws + 35061760);      //   4194304 B  [128][256][32]  f32
  short* A0bf= (short*)(ws + 39256064);      // 268435456 B  tiled bf16 A0

  bool big = ws_size >= (size_t)307691520;

  k_prep  <<<40,   256, 0, stream>>>(comp1, bases1, comp2, bases2, w1T, w2T);
  k_xw    <<<1024, 256, 0, stream>>>(X, sel, w1T, xwT);
  if (big) {
    k_conv    <<<2048, 256, 0, stream>>>(A0, A0bf);
    k_h1_tiled<<<1024, 256, 0, stream>>>(A0bf, xwT, h1p);
    k_red     <<<64,   256, 0, stream>>>(h1p, bias1, h1b, 64);
  } else {
    k_h1_direct<<<256, 256, 0, stream>>>(A0, xwT, h1p);
    k_red      <<<64,  256, 0, stream>>>(h1p, bias1, h1b, 16);
  }
  k_h2    <<<64,   256, 0, stream>>>(w2T, h1b, H2T);
  k_out   <<<128,  256, 0, stream>>>(A1, H2T, outp);
  k_outred<<<8,    256, 0, stream>>>(outp, bias2, out);
}

// Round 8
// 238.668 us; speedup vs baseline: 1.6231x; 1.6231x over previous
//
#include <hip/hip_runtime.h>

// Problem constants
#define RR_ 16      // num_rels
#define N2_ 8192
#define N1_ 1024
#define NOUT_ 256
#define F_ 128
#define E_ 64
#define C_ 32
#define KBIG_ 131072   // R*N2

typedef __attribute__((ext_vector_type(4))) float f32x4;
typedef __attribute__((ext_vector_type(8))) short short8;

#define MFMA(a,b,c) __builtin_amdgcn_mfma_f32_16x16x32_bf16((a),(b),(c),0,0,0)

__device__ __forceinline__ unsigned short f2bf(float f) {
  unsigned int u = __builtin_bit_cast(unsigned int, f);
  u += 0x7fffu + ((u >> 16) & 1u);              // RNE
  return (unsigned short)(u >> 16);
}

__device__ __forceinline__ short8 cvt8(f32x4 v0, f32x4 v1) {
  short8 r;
  r[0] = (short)f2bf(v0[0]); r[1] = (short)f2bf(v0[1]);
  r[2] = (short)f2bf(v0[2]); r[3] = (short)f2bf(v0[3]);
  r[4] = (short)f2bf(v1[0]); r[5] = (short)f2bf(v1[1]);
  r[6] = (short)f2bf(v1[2]); r[7] = (short)f2bf(v1[3]);
  return r;
}

// ---------------------------------------------------------------------------
// K1: prep — w1T[r][h][f], w2T[r][c][h] (bf16); zero h1f; out = bias2
// grid: 49 blocks x 256
// ---------------------------------------------------------------------------
__global__ __launch_bounds__(256) void k_prep(
    const float* __restrict__ comp1, const float* __restrict__ bases1,
    const float* __restrict__ comp2, const float* __restrict__ bases2,
    const float* __restrict__ bias2,
    short* __restrict__ w1T, short* __restrict__ w2T,
    float* __restrict__ h1f, float* __restrict__ out)
{
  int bid = blockIdx.x, t = threadIdx.x;
  if (bid < 32) {                       // w1T: 131072 els, w1T[r][h][f] = sum_b comp1[r][b]*bases1[b][f][h]
    int base = bid * 4096;
    for (int i = 0; i < 16; ++i) {
      int e = base + i * 256 + t;
      int r = e >> 13, rem = e & 8191;
      int h = rem >> 7, f = rem & 127;
      float s = 0.f;
      #pragma unroll
      for (int b = 0; b < 16; ++b) s += comp1[r * 16 + b] * bases1[b * 8192 + f * 64 + h];
      w1T[e] = (short)f2bf(s);
    }
  } else if (bid < 40) {                // w2T: 32768 els, w2T[r][c][h] = sum_b comp2[r][b]*bases2[b][h][c]
    int base = (bid - 32) * 4096;
    for (int i = 0; i < 16; ++i) {
      int e = base + i * 256 + t;
      int r = e >> 11, rem = e & 2047;
      int c = rem >> 6, h = rem & 63;
      float s = 0.f;
      #pragma unroll
      for (int b = 0; b < 16; ++b) s += comp2[r * 16 + b] * bases2[b * 2048 + h * 32 + c];
      w2T[e] = (short)f2bf(s);
    }
  } else if (bid < 48) {                // zero h1f (65536 floats)
    int base = (bid - 40) * 8192;
    f32x4 z = {0.f, 0.f, 0.f, 0.f};
    for (int i = 0; i < 8; ++i)
      *(f32x4*)(h1f + base + i * 1024 + t * 4) = z;
  } else {                              // out init = bias2 (8192 els)
    for (int i = 0; i < 32; ++i) {
      int e = i * 256 + t;
      out[e] = bias2[e & 31];
    }
  }
}

// ---------------------------------------------------------------------------
// K2: xwT[h][r*8192+n2] = sum_f w1T[r][h][f] * X[sel[n2]][f]
// per r: GEMM M=64(h) x N=8192(n2) x K=128(f). 4096 waves, grid 1024x256.
// ---------------------------------------------------------------------------
__global__ __launch_bounds__(256) void k_xw(
    const float* __restrict__ X, const int* __restrict__ sel,
    const short* __restrict__ w1T, short* __restrict__ xwT)
{
  int w = blockIdx.x * 4 + (threadIdx.x >> 6);
  int lane = threadIdx.x & 63, lr = lane & 15, lg = lane >> 4;
  int r = w >> 8;
  int n0 = (w & 255) * 32;

  // sel may be int64 (jax x64) — detect via arange pattern, values fit int32.
  bool is64 = (sel[1] == 0 && sel[2] == 1);
  int i0 = is64 ? sel[2 * (n0 + lr)] : sel[n0 + lr];
  int i1 = is64 ? sel[2 * (n0 + 16 + lr)] : sel[n0 + 16 + lr];

  const short* aBase = w1T + r * 8192 + lr * 128 + 8 * lg;
  const float* b0p = X + (size_t)i0 * 128 + 8 * lg;
  const float* b1p = X + (size_t)i1 * 128 + 8 * lg;

  f32x4 acc[4][2] = {};
  #pragma unroll
  for (int ks = 0; ks < 4; ++ks) {
    short8 a[4];
    #pragma unroll
    for (int mf = 0; mf < 4; ++mf)
      a[mf] = *(const short8*)(aBase + mf * 2048 + ks * 32);
    short8 b[2];
    b[0] = cvt8(*(const f32x4*)(b0p + ks * 32), *(const f32x4*)(b0p + ks * 32 + 4));
    b[1] = cvt8(*(const f32x4*)(b1p + ks * 32), *(const f32x4*)(b1p + ks * 32 + 4));
    #pragma unroll
    for (int mf = 0; mf < 4; ++mf)
      #pragma unroll
      for (int nf = 0; nf < 2; ++nf)
        acc[mf][nf] = MFMA(a[mf], b[nf], acc[mf][nf]);
  }
  #pragma unroll
  for (int mf = 0; mf < 4; ++mf)
    #pragma unroll
    for (int nf = 0; nf < 2; ++nf)
      #pragma unroll
      for (int rr = 0; rr < 4; ++rr) {
        int h = mf * 16 + 4 * lg + rr;
        int col = r * 8192 + n0 + nf * 16 + lr;
        xwT[(size_t)h * KBIG_ + col] = (short)f2bf(acc[mf][nf][rr]);
      }
}

// ---------------------------------------------------------------------------
// K3 (v6): h1f += A0[1024 x 131072] @ xw  (B^T = xwT).  Split-K, atomics.
// EXACT v1 structure (direct nontemporal loads, no LDS, no waits) with ONE
// change: 2x the waves. 256 K-chunks x Kc=512 -> 4096 waves = 16/CU resident
// (v1: 2048 waves = 8/CU, grid-limited). __launch_bounds__(256,4) forces
// VGPR<=128 so 4 waves/SIMD fit (132 VGPR would cap at 3).
// ---------------------------------------------------------------------------
__global__ __launch_bounds__(256, 4) void k_h1(
    const float* __restrict__ A0, const short* __restrict__ xwT,
    float* __restrict__ h1f)
{
  int w = blockIdx.x * 4 + (threadIdx.x >> 6);
  int lane = threadIdx.x & 63, lr = lane & 15, lg = lane >> 4;
  int mt = w >> 8;          // 0..15
  int ch = w & 255;         // 0..255
  int m0 = mt * 64;
  size_t kc = (size_t)ch * 512;

  const float* aBase = A0 + (size_t)(m0 + lr) * KBIG_ + kc + 8 * lg;
  const short* bBase = xwT + (size_t)lr * KBIG_ + kc + 8 * lg;

  f32x4 acc[4][4] = {};
  for (int ks = 0; ks < 16; ++ks) {
    short8 a[4];
    #pragma unroll
    for (int mf = 0; mf < 4; ++mf) {
      const float* p = aBase + (size_t)mf * 16 * KBIG_ + ks * 32;
      f32x4 v0 = __builtin_nontemporal_load((const f32x4*)p);
      f32x4 v1 = __builtin_nontemporal_load((const f32x4*)p + 1);
      a[mf] = cvt8(v0, v1);
    }
    short8 b[4];
    #pragma unroll
    for (int nf = 0; nf < 4; ++nf)
      b[nf] = *(const short8*)(bBase + (size_t)nf * 16 * KBIG_ + ks * 32);
    #pragma unroll
    for (int mf = 0; mf < 4; ++mf)
      #pragma unroll
      for (int nf = 0; nf < 4; ++nf)
        acc[mf][nf] = MFMA(a[mf], b[nf], acc[mf][nf]);
  }
  #pragma unroll
  for (int mf = 0; mf < 4; ++mf)
    #pragma unroll
    for (int nf = 0; nf < 4; ++nf)
      #pragma unroll
      for (int rr = 0; rr < 4; ++rr)
        atomicAdd(h1f + (m0 + mf * 16 + 4 * lg + rr) * 64 + nf * 16 + lr,
                  acc[mf][nf][rr]);
}

// ---------------------------------------------------------------------------
// K3b: h1b = bf16(relu(h1f + bias1))   (65536 els; 32 blocks x 256)
// ---------------------------------------------------------------------------
__global__ __launch_bounds__(256) void k_relu(
    const float* __restrict__ h1f, const float* __restrict__ bias1,
    short* __restrict__ h1b)
{
  int idx = (blockIdx.x * 256 + threadIdx.x) * 8;
  f32x4 v0 = *(const f32x4*)(h1f + idx);
  f32x4 v1 = *(const f32x4*)(h1f + idx + 4);
  int h = idx & 63;
  short8 o;
  #pragma unroll
  for (int j = 0; j < 4; ++j) {
    float x = v0[j] + bias1[h + j];     x = x > 0.f ? x : 0.f; o[j] = (short)f2bf(x);
  }
  #pragma unroll
  for (int j = 0; j < 4; ++j) {
    float x = v1[j] + bias1[h + 4 + j]; x = x > 0.f ? x : 0.f; o[4 + j] = (short)f2bf(x);
  }
  *(short8*)(h1b + idx) = o;
}

// ---------------------------------------------------------------------------
// K4a: H2T[c][r*1024+m] = sum_h w2T[r][c][h] * h1b[m][h]
// per r: M=32(c, 2 mf) x N=1024(m) x K=64.  wave Ntile=64; 256 waves = 64 blocks.
// ---------------------------------------------------------------------------
__global__ __launch_bounds__(256) void k_h2(
    const short* __restrict__ w2T, const short* __restrict__ h1b,
    short* __restrict__ H2T)
{
  int w = blockIdx.x * 4 + (threadIdx.x >> 6);
  int lane = threadIdx.x & 63, lr = lane & 15, lg = lane >> 4;
  int r = w >> 4;
  int n0 = (w & 15) * 64;

  f32x4 acc[2][4] = {};
  #pragma unroll
  for (int ks = 0; ks < 2; ++ks) {
    short8 a[2];
    #pragma unroll
    for (int mf = 0; mf < 2; ++mf)
      a[mf] = *(const short8*)(w2T + r * 2048 + (mf * 16 + lr) * 64 + ks * 32 + 8 * lg);
    short8 b[4];
    #pragma unroll
    for (int nf = 0; nf < 4; ++nf)
      b[nf] = *(const short8*)(h1b + (size_t)(n0 + nf * 16 + lr) * 64 + ks * 32 + 8 * lg);
    #pragma unroll
    for (int mf = 0; mf < 2; ++mf)
      #pragma unroll
      for (int nf = 0; nf < 4; ++nf)
        acc[mf][nf] = MFMA(a[mf], b[nf], acc[mf][nf]);
  }
  #pragma unroll
  for (int mf = 0; mf < 2; ++mf)
    #pragma unroll
    for (int nf = 0; nf < 4; ++nf)
      #pragma unroll
      for (int rr = 0; rr < 4; ++rr) {
        int c = mf * 16 + 4 * lg + rr;
        int col = r * 1024 + n0 + nf * 16 + lr;
        H2T[(size_t)c * 16384 + col] = (short)f2bf(acc[mf][nf][rr]);
      }
}

// ---------------------------------------------------------------------------
// K4b: out += A1[256 x 16384] @ H2   (B^T = H2T). Split-K, atomics into out.
// wave: Mtile=64 (4 mf) x N=32 (2 nf), Kc=128 (4 ksteps). 512 waves = 128 blocks.
// ---------------------------------------------------------------------------
__global__ __launch_bounds__(256) void k_out(
    const float* __restrict__ A1, const short* __restrict__ H2T,
    float* __restrict__ out)
{
  int w = blockIdx.x * 4 + (threadIdx.x >> 6);
  int lane = threadIdx.x & 63, lr = lane & 15, lg = lane >> 4;
  int mt = w >> 7;          // 0..3
  int ch = w & 127;         // 0..127
  int m0 = mt * 64;
  size_t kc = (size_t)ch * 128;

  const float* aBase = A1 + (size_t)(m0 + lr) * 16384 + kc + 8 * lg;
  const short* bBase = H2T + (size_t)lr * 16384 + kc + 8 * lg;

  f32x4 acc[4][2] = {};
  #pragma unroll
  for (int ks = 0; ks < 4; ++ks) {
    short8 a[4];
    #pragma unroll
    for (int mf = 0; mf < 4; ++mf) {
      const float* p = aBase + (size_t)mf * 16 * 16384 + ks * 32;
      f32x4 v0 = __builtin_nontemporal_load((const f32x4*)p);
      f32x4 v1 = __builtin_nontemporal_load((const f32x4*)p + 1);
      a[mf] = cvt8(v0, v1);
    }
    short8 b[2];
    #pragma unroll
    for (int nf = 0; nf < 2; ++nf)
      b[nf] = *(const short8*)(bBase + (size_t)nf * 16 * 16384 + ks * 32);
    #pragma unroll
    for (int mf = 0; mf < 4; ++mf)
      #pragma unroll
      for (int nf = 0; nf < 2; ++nf)
        acc[mf][nf] = MFMA(a[mf], b[nf], acc[mf][nf]);
  }
  #pragma unroll
  for (int mf = 0; mf < 4; ++mf)
    #pragma unroll
    for (int nf = 0; nf < 2; ++nf)
      #pragma unroll
      for (int rr = 0; rr < 4; ++rr)
        atomicAdd(out + (m0 + mf * 16 + 4 * lg + rr) * 32 + nf * 16 + lr,
                  acc[mf][nf][rr]);
}

// ---------------------------------------------------------------------------
extern "C" void kernel_launch(void* const* d_in, const int* in_sizes, int n_in,
                              void* d_out, int out_size, void* d_ws, size_t ws_size,
                              hipStream_t stream) {
  (void)in_sizes; (void)n_in; (void)out_size; (void)ws_size;
  const float* X      = (const float*)d_in[0];
  const int*   sel    = (const int*)  d_in[1];
  const float* A0     = (const float*)d_in[2];
  const float* A1     = (const float*)d_in[3];
  const float* comp1  = (const float*)d_in[4];
  const float* bases1 = (const float*)d_in[5];
  const float* comp2  = (const float*)d_in[6];
  const float* bases2 = (const float*)d_in[7];
  const float* bias1  = (const float*)d_in[8];
  const float* bias2  = (const float*)d_in[9];
  float* out = (float*)d_out;

  char* ws = (char*)d_ws;
  short* w1T = (short*)(ws);                 //   262144 B  [16][64][128] bf16
  short* w2T = (short*)(ws + 262144);        //    65536 B  [16][32][64]  bf16
  short* xwT = (short*)(ws + 327680);        // 16777216 B  [64][131072]  bf16
  float* h1f = (float*)(ws + 17104896);      //   262144 B  [1024][64]    f32
  short* h1b = (short*)(ws + 17367040);      //   131072 B  [1024][64]    bf16
  short* H2T = (short*)(ws + 17498112);      //  1048576 B  [32][16384]   bf16

  k_prep<<<49,   256, 0, stream>>>(comp1, bases1, comp2, bases2, bias2, w1T, w2T, h1f, out);
  k_xw  <<<1024, 256, 0, stream>>>(X, sel, w1T, xwT);
  k_h1  <<<1024, 256, 0, stream>>>(A0, xwT, h1f);
  k_relu<<<32,   256, 0, stream>>>(h1f, bias1, h1b);
  k_h2  <<<64,   256, 0, stream>>>(w2T, h1b, H2T);
  k_out <<<128,  256, 0, stream>>>(A1, H2T, out);
}

// Round 9
// 225.243 us; speedup vs baseline: 1.7199x; 1.0596x over previous
//
#include <hip/hip_runtime.h>

// Problem constants
#define RR_ 16      // num_rels
#define N2_ 8192
#define N1_ 1024
#define NOUT_ 256
#define F_ 128
#define E_ 64
#define C_ 32
#define KBIG_ 131072   // R*N2

typedef __attribute__((ext_vector_type(4))) float f32x4;
typedef __attribute__((ext_vector_type(8))) short short8;

#define MFMA(a,b,c) __builtin_amdgcn_mfma_f32_16x16x32_bf16((a),(b),(c),0,0,0)

__device__ __forceinline__ unsigned short f2bf(float f) {
  unsigned int u = __builtin_bit_cast(unsigned int, f);
  u += 0x7fffu + ((u >> 16) & 1u);              // RNE
  return (unsigned short)(u >> 16);
}

__device__ __forceinline__ short8 cvt8(f32x4 v0, f32x4 v1) {
  short8 r;
  r[0] = (short)f2bf(v0[0]); r[1] = (short)f2bf(v0[1]);
  r[2] = (short)f2bf(v0[2]); r[3] = (short)f2bf(v0[3]);
  r[4] = (short)f2bf(v1[0]); r[5] = (short)f2bf(v1[1]);
  r[6] = (short)f2bf(v1[2]); r[7] = (short)f2bf(v1[3]);
  return r;
}

// ---------------------------------------------------------------------------
// K1: prep — w1T[r][h][f], w2T[r][c][h] (bf16); zero h1f; out = bias2
// grid: 49 blocks x 256
// ---------------------------------------------------------------------------
__global__ __launch_bounds__(256) void k_prep(
    const float* __restrict__ comp1, const float* __restrict__ bases1,
    const float* __restrict__ comp2, const float* __restrict__ bases2,
    const float* __restrict__ bias2,
    short* __restrict__ w1T, short* __restrict__ w2T,
    float* __restrict__ h1f, float* __restrict__ out)
{
  int bid = blockIdx.x, t = threadIdx.x;
  if (bid < 32) {                       // w1T: 131072 els, w1T[r][h][f] = sum_b comp1[r][b]*bases1[b][f][h]
    int base = bid * 4096;
    for (int i = 0; i < 16; ++i) {
      int e = base + i * 256 + t;
      int r = e >> 13, rem = e & 8191;
      int h = rem >> 7, f = rem & 127;
      float s = 0.f;
      #pragma unroll
      for (int b = 0; b < 16; ++b) s += comp1[r * 16 + b] * bases1[b * 8192 + f * 64 + h];
      w1T[e] = (short)f2bf(s);
    }
  } else if (bid < 40) {                // w2T: 32768 els, w2T[r][c][h] = sum_b comp2[r][b]*bases2[b][h][c]
    int base = (bid - 32) * 4096;
    for (int i = 0; i < 16; ++i) {
      int e = base + i * 256 + t;
      int r = e >> 11, rem = e & 2047;
      int c = rem >> 6, h = rem & 63;
      float s = 0.f;
      #pragma unroll
      for (int b = 0; b < 16; ++b) s += comp2[r * 16 + b] * bases2[b * 2048 + h * 32 + c];
      w2T[e] = (short)f2bf(s);
    }
  } else if (bid < 48) {                // zero h1f (65536 floats)
    int base = (bid - 40) * 8192;
    f32x4 z = {0.f, 0.f, 0.f, 0.f};
    for (int i = 0; i < 8; ++i)
      *(f32x4*)(h1f + base + i * 1024 + t * 4) = z;
  } else {                              // out init = bias2 (8192 els)
    for (int i = 0; i < 32; ++i) {
      int e = i * 256 + t;
      out[e] = bias2[e & 31];
    }
  }
}

// ---------------------------------------------------------------------------
// K2: xwT[h][r*8192+n2] = sum_f w1T[r][h][f] * X[sel[n2]][f]
// per r: GEMM M=64(h) x N=8192(n2) x K=128(f). 4096 waves, grid 1024x256.
// ---------------------------------------------------------------------------
__global__ __launch_bounds__(256) void k_xw(
    const float* __restrict__ X, const int* __restrict__ sel,
    const short* __restrict__ w1T, short* __restrict__ xwT)
{
  int w = blockIdx.x * 4 + (threadIdx.x >> 6);
  int lane = threadIdx.x & 63, lr = lane & 15, lg = lane >> 4;
  int r = w >> 8;
  int n0 = (w & 255) * 32;

  // sel may be int64 (jax x64) — detect via arange pattern, values fit int32.
  bool is64 = (sel[1] == 0 && sel[2] == 1);
  int i0 = is64 ? sel[2 * (n0 + lr)] : sel[n0 + lr];
  int i1 = is64 ? sel[2 * (n0 + 16 + lr)] : sel[n0 + 16 + lr];

  const short* aBase = w1T + r * 8192 + lr * 128 + 8 * lg;
  const float* b0p = X + (size_t)i0 * 128 + 8 * lg;
  const float* b1p = X + (size_t)i1 * 128 + 8 * lg;

  f32x4 acc[4][2] = {};
  #pragma unroll
  for (int ks = 0; ks < 4; ++ks) {
    short8 a[4];
    #pragma unroll
    for (int mf = 0; mf < 4; ++mf)
      a[mf] = *(const short8*)(aBase + mf * 2048 + ks * 32);
    short8 b[2];
    b[0] = cvt8(*(const f32x4*)(b0p + ks * 32), *(const f32x4*)(b0p + ks * 32 + 4));
    b[1] = cvt8(*(const f32x4*)(b1p + ks * 32), *(const f32x4*)(b1p + ks * 32 + 4));
    #pragma unroll
    for (int mf = 0; mf < 4; ++mf)
      #pragma unroll
      for (int nf = 0; nf < 2; ++nf)
        acc[mf][nf] = MFMA(a[mf], b[nf], acc[mf][nf]);
  }
  #pragma unroll
  for (int mf = 0; mf < 4; ++mf)
    #pragma unroll
    for (int nf = 0; nf < 2; ++nf)
      #pragma unroll
      for (int rr = 0; rr < 4; ++rr) {
        int h = mf * 16 + 4 * lg + rr;
        int col = r * 8192 + n0 + nf * 16 + lr;
        xwT[(size_t)h * KBIG_ + col] = (short)f2bf(acc[mf][nf][rr]);
      }
}

// ---------------------------------------------------------------------------
// K3 (v7): h1f += A0[1024 x 131072] @ xw  (B^T = xwT).  Split-K, atomics.
// Round-8 structure; ONE change: A0 loads are PLAIN (no nontemporal) — A/B
// test whether nt was depressing L3 retention of the A0 stream.
// 256 K-chunks x Kc=512 -> 4096 waves = 16/CU.
// ---------------------------------------------------------------------------
__global__ __launch_bounds__(256, 4) void k_h1(
    const float* __restrict__ A0, const short* __restrict__ xwT,
    float* __restrict__ h1f)
{
  int w = blockIdx.x * 4 + (threadIdx.x >> 6);
  int lane = threadIdx.x & 63, lr = lane & 15, lg = lane >> 4;
  int mt = w >> 8;          // 0..15
  int ch = w & 255;         // 0..255
  int m0 = mt * 64;
  size_t kc = (size_t)ch * 512;

  const float* aBase = A0 + (size_t)(m0 + lr) * KBIG_ + kc + 8 * lg;
  const short* bBase = xwT + (size_t)lr * KBIG_ + kc + 8 * lg;

  f32x4 acc[4][4] = {};
  for (int ks = 0; ks < 16; ++ks) {
    short8 a[4];
    #pragma unroll
    for (int mf = 0; mf < 4; ++mf) {
      const float* p = aBase + (size_t)mf * 16 * KBIG_ + ks * 32;
      f32x4 v0 = *(const f32x4*)p;
      f32x4 v1 = *((const f32x4*)p + 1);
      a[mf] = cvt8(v0, v1);
    }
    short8 b[4];
    #pragma unroll
    for (int nf = 0; nf < 4; ++nf)
      b[nf] = *(const short8*)(bBase + (size_t)nf * 16 * KBIG_ + ks * 32);
    #pragma unroll
    for (int mf = 0; mf < 4; ++mf)
      #pragma unroll
      for (int nf = 0; nf < 4; ++nf)
        acc[mf][nf] = MFMA(a[mf], b[nf], acc[mf][nf]);
  }
  #pragma unroll
  for (int mf = 0; mf < 4; ++mf)
    #pragma unroll
    for (int nf = 0; nf < 4; ++nf)
      #pragma unroll
      for (int rr = 0; rr < 4; ++rr)
        atomicAdd(h1f + (m0 + mf * 16 + 4 * lg + rr) * 64 + nf * 16 + lr,
                  acc[mf][nf][rr]);
}

// ---------------------------------------------------------------------------
// K4a (fused): H2T[c][r*1024+m] = sum_h w2T[r][c][h] * relu(h1f[m][h]+bias1[h])
// bias+ReLU+bf16-cvt folded into the B-operand load (replaces k_relu).
// per r: M=32(c, 2 mf) x N=1024(m) x K=64.  wave Ntile=64; 256 waves = 64 blocks.
// ---------------------------------------------------------------------------
__global__ __launch_bounds__(256) void k_h2(
    const short* __restrict__ w2T, const float* __restrict__ h1f,
    const float* __restrict__ bias1, short* __restrict__ H2T)
{
  int w = blockIdx.x * 4 + (threadIdx.x >> 6);
  int lane = threadIdx.x & 63, lr = lane & 15, lg = lane >> 4;
  int r = w >> 4;
  int n0 = (w & 15) * 64;

  f32x4 acc[2][4] = {};
  #pragma unroll
  for (int ks = 0; ks < 2; ++ks) {
    short8 a[2];
    #pragma unroll
    for (int mf = 0; mf < 2; ++mf)
      a[mf] = *(const short8*)(w2T + r * 2048 + (mf * 16 + lr) * 64 + ks * 32 + 8 * lg);
    int hof = ks * 32 + 8 * lg;
    f32x4 bv0 = *(const f32x4*)(bias1 + hof);
    f32x4 bv1 = *(const f32x4*)(bias1 + hof + 4);
    short8 b[4];
    #pragma unroll
    for (int nf = 0; nf < 4; ++nf) {
      const float* hp = h1f + (size_t)(n0 + nf * 16 + lr) * 64 + hof;
      f32x4 v0 = *(const f32x4*)hp;
      f32x4 v1 = *(const f32x4*)(hp + 4);
      #pragma unroll
      for (int j = 0; j < 4; ++j) {
        float x0 = v0[j] + bv0[j]; v0[j] = x0 > 0.f ? x0 : 0.f;
        float x1 = v1[j] + bv1[j]; v1[j] = x1 > 0.f ? x1 : 0.f;
      }
      b[nf] = cvt8(v0, v1);
    }
    #pragma unroll
    for (int mf = 0; mf < 2; ++mf)
      #pragma unroll
      for (int nf = 0; nf < 4; ++nf)
        acc[mf][nf] = MFMA(a[mf], b[nf], acc[mf][nf]);
  }
  #pragma unroll
  for (int mf = 0; mf < 2; ++mf)
    #pragma unroll
    for (int nf = 0; nf < 4; ++nf)
      #pragma unroll
      for (int rr = 0; rr < 4; ++rr) {
        int c = mf * 16 + 4 * lg + rr;
        int col = r * 1024 + n0 + nf * 16 + lr;
        H2T[(size_t)c * 16384 + col] = (short)f2bf(acc[mf][nf][rr]);
      }
}

// ---------------------------------------------------------------------------
// K4b: out += A1[256 x 16384] @ H2   (B^T = H2T). Split-K, atomics into out.
// wave: Mtile=64 (4 mf) x N=32 (2 nf), Kc=128 (4 ksteps). 512 waves = 128 blocks.
// ---------------------------------------------------------------------------
__global__ __launch_bounds__(256) void k_out(
    const float* __restrict__ A1, const short* __restrict__ H2T,
    float* __restrict__ out)
{
  int w = blockIdx.x * 4 + (threadIdx.x >> 6);
  int lane = threadIdx.x & 63, lr = lane & 15, lg = lane >> 4;
  int mt = w >> 7;          // 0..3
  int ch = w & 127;         // 0..127
  int m0 = mt * 64;
  size_t kc = (size_t)ch * 128;

  const float* aBase = A1 + (size_t)(m0 + lr) * 16384 + kc + 8 * lg;
  const short* bBase = H2T + (size_t)lr * 16384 + kc + 8 * lg;

  f32x4 acc[4][2] = {};
  #pragma unroll
  for (int ks = 0; ks < 4; ++ks) {
    short8 a[4];
    #pragma unroll
    for (int mf = 0; mf < 4; ++mf) {
      const float* p = aBase + (size_t)mf * 16 * 16384 + ks * 32;
      f32x4 v0 = __builtin_nontemporal_load((const f32x4*)p);
      f32x4 v1 = __builtin_nontemporal_load((const f32x4*)p + 1);
      a[mf] = cvt8(v0, v1);
    }
    short8 b[2];
    #pragma unroll
    for (int nf = 0; nf < 2; ++nf)
      b[nf] = *(const short8*)(bBase + (size_t)nf * 16 * 16384 + ks * 32);
    #pragma unroll
    for (int mf = 0; mf < 4; ++mf)
      #pragma unroll
      for (int nf = 0; nf < 2; ++nf)
        acc[mf][nf] = MFMA(a[mf], b[nf], acc[mf][nf]);
  }
  #pragma unroll
  for (int mf = 0; mf < 4; ++mf)
    #pragma unroll
    for (int nf = 0; nf < 2; ++nf)
      #pragma unroll
      for (int rr = 0; rr < 4; ++rr)
        atomicAdd(out + (m0 + mf * 16 + 4 * lg + rr) * 32 + nf * 16 + lr,
                  acc[mf][nf][rr]);
}

// ---------------------------------------------------------------------------
extern "C" void kernel_launch(void* const* d_in, const int* in_sizes, int n_in,
                              void* d_out, int out_size, void* d_ws, size_t ws_size,
                              hipStream_t stream) {
  (void)in_sizes; (void)n_in; (void)out_size; (void)ws_size;
  const float* X      = (const float*)d_in[0];
  const int*   sel    = (const int*)  d_in[1];
  const float* A0     = (const float*)d_in[2];
  const float* A1     = (const float*)d_in[3];
  const float* comp1  = (const float*)d_in[4];
  const float* bases1 = (const float*)d_in[5];
  const float* comp2  = (const float*)d_in[6];
  const float* bases2 = (const float*)d_in[7];
  const float* bias1  = (const float*)d_in[8];
  const float* bias2  = (const float*)d_in[9];
  float* out = (float*)d_out;

  char* ws = (char*)d_ws;
  short* w1T = (short*)(ws);                 //   262144 B  [16][64][128] bf16
  short* w2T = (short*)(ws + 262144);        //    65536 B  [16][32][64]  bf16
  short* xwT = (short*)(ws + 327680);        // 16777216 B  [64][131072]  bf16
  float* h1f = (float*)(ws + 17104896);      //   262144 B  [1024][64]    f32
  short* H2T = (short*)(ws + 17498112);      //  1048576 B  [32][16384]   bf16

  k_prep<<<49,   256, 0, stream>>>(comp1, bases1, comp2, bases2, bias2, w1T, w2T, h1f, out);
  k_xw  <<<1024, 256, 0, stream>>>(X, sel, w1T, xwT);
  k_h1  <<<1024, 256, 0, stream>>>(A0, xwT, h1f);
  k_h2  <<<64,   256, 0, stream>>>(w2T, h1f, bias1, H2T);
  k_out <<<128,  256, 0, stream>>>(A1, H2T, out);
}